// Round 12
// baseline (283.071 us; speedup 1.0000x reference)
//
#include <hip/hip_runtime.h>
#include <hip/hip_bf16.h>
#include <math.h>

typedef __bf16 bf16;
typedef __bf16 bf16x8 __attribute__((ext_vector_type(8)));
typedef float f32x4 __attribute__((ext_vector_type(4)));
typedef float f32x16 __attribute__((ext_vector_type(16)));

#define B_ 4
#define T_ 128
#define D_ 256
#define FF_ 1024
#define HD_ 32
#define VOCAB_ 32000
#define NC_ 516    // iface cols = MH*(4*HD+1)
#define KBIG_ 384  // D + MD

// ---------------- weight transpose (blocks 0..419) + embed+LN1 (blocks 420..931) ----------------
struct TJob { const float* src; bf16* dst; int K; int N; int blk0; };
struct TJobs { TJob j[9]; };
__global__ __launch_bounds__(256) void k_tr_embed(TJobs js, const int* __restrict__ ids,
                                                  const float* __restrict__ tok,
                                                  const float* __restrict__ pos,
                                                  const float* __restrict__ g,
                                                  const float* __restrict__ b,
                                                  float* __restrict__ X, bf16* __restrict__ out,
                                                  unsigned* __restrict__ flags) {
    int bid = blockIdx.x;
    if (bid == 0 && threadIdx.x == 0) flags[0] = 0u;   // reset handshake for this launch
    if (bid < 420) {
        __shared__ float tile[64][65];
        int r = 0;
#pragma unroll
        for (int i = 1; i < 9; i++) if (bid >= js.j[i].blk0) r = i;
        TJob jb = js.j[r];
        int local = bid - jb.blk0;
        int tiles_k = jb.K >> 6;
        int ik = local % tiles_k, in = local / tiles_k;
        int k0 = ik * 64, n0 = in * 64;
        int tx = threadIdx.x & 63, ty = threadIdx.x >> 6;
#pragma unroll
        for (int rr = 0; rr < 64; rr += 4) {
            int kk = k0 + rr + ty, nn = n0 + tx;
            tile[rr + ty][tx] = (nn < jb.N) ? jb.src[(size_t)kk * jb.N + nn] : 0.f;
        }
        __syncthreads();
#pragma unroll
        for (int rr = 0; rr < 64; rr += 4) {
            int nn = n0 + rr + ty, kk = k0 + tx;
            jb.dst[(size_t)nn * jb.K + kk] = (bf16)tile[tx][rr + ty];
        }
        return;
    }
    // embed + LN1(layer0)
    int row = bid - 420;
    int d   = threadIdx.x;
    int t   = row & (T_ - 1);
    int id  = ids[row];
    float v = tok[(size_t)id * D_ + d] + pos[(size_t)t * D_ + d];
    X[(size_t)row * D_ + d] = v;
    float s1 = v, s2 = v * v;
#pragma unroll
    for (int off = 32; off > 0; off >>= 1) {
        s1 += __shfl_xor(s1, off);
        s2 += __shfl_xor(s2, off);
    }
    __shared__ float r1[4], r2[4];
    int wid = d >> 6, lane = d & 63;
    if (lane == 0) { r1[wid] = s1; r2[wid] = s2; }
    __syncthreads();
    float tot1 = r1[0] + r1[1] + r1[2] + r1[3];
    float tot2 = r2[0] + r2[1] + r2[2] + r2[3];
    float mean = tot1 * (1.f / D_);
    float var  = tot2 * (1.f / D_) - mean * mean;
    float rs   = rsqrtf(var + 1e-5f);
    out[(size_t)row * D_ + d] = (bf16)((v - mean) * rs * g[d] + b[d]);
}

// ---------------- layernorm (row of 256) -> bf16 out ----------------
__global__ void k_ln(const float* __restrict__ X, const float* __restrict__ g,
                     const float* __restrict__ b, bf16* __restrict__ out, int ostride) {
    int row = blockIdx.x;
    int d   = threadIdx.x;
    float v = X[(size_t)row * D_ + d];
    float s1 = v, s2 = v * v;
#pragma unroll
    for (int off = 32; off > 0; off >>= 1) {
        s1 += __shfl_xor(s1, off);
        s2 += __shfl_xor(s2, off);
    }
    __shared__ float r1[4], r2[4];
    int wid = d >> 6, lane = d & 63;
    if (lane == 0) { r1[wid] = s1; r2[wid] = s2; }
    __syncthreads();
    float tot1 = r1[0] + r1[1] + r1[2] + r1[3];
    float tot2 = r2[0] + r2[1] + r2[2] + r2[3];
    float mean = tot1 * (1.f / D_);
    float var  = tot2 * (1.f / D_) - mean * mean;
    float rs   = rsqrtf(var + 1e-5f);
    out[(size_t)row * ostride + d] = (bf16)((v - mean) * rs * g[d] + b[d]);
}

// ---------------- direct-fragment GEMM (no LDS, no barriers) ----------------
template <bool BIAS, bool GELU_, bool RESID, bool OBF16>
__global__ __launch_bounds__(256) void k_dgemm(const bf16* __restrict__ A, int lda,
                                               const bf16* __restrict__ BT,
                                               const float* __restrict__ bias,
                                               float* __restrict__ Cf, bf16* __restrict__ Cb,
                                               int ldc, int N, int K) {
    int tid = threadIdx.x;
    int lane = tid & 63, wid = tid >> 6;
    int wm = wid >> 1, wn = wid & 1;
    int m0 = blockIdx.y * 64, n0 = blockIdx.x * 64;
    int r = lane & 15, q = lane >> 4;

    const bf16* Ab = A  + (size_t)(m0 + wm * 32 + r) * lda + q * 8;
    const bf16* Bb = BT + (size_t)(n0 + wn * 32 + r) * K   + q * 8;

    f32x4 acc[2][2] = {};
#pragma unroll 4
    for (int k0 = 0; k0 < K; k0 += 32) {
        bf16x8 a0 = *(const bf16x8*)(Ab + k0);
        bf16x8 a1 = *(const bf16x8*)(Ab + (size_t)16 * lda + k0);
        bf16x8 b0 = *(const bf16x8*)(Bb + k0);
        bf16x8 b1 = *(const bf16x8*)(Bb + (size_t)16 * K + k0);
        acc[0][0] = __builtin_amdgcn_mfma_f32_16x16x32_bf16(a0, b0, acc[0][0], 0, 0, 0);
        acc[0][1] = __builtin_amdgcn_mfma_f32_16x16x32_bf16(a0, b1, acc[0][1], 0, 0, 0);
        acc[1][0] = __builtin_amdgcn_mfma_f32_16x16x32_bf16(a1, b0, acc[1][0], 0, 0, 0);
        acc[1][1] = __builtin_amdgcn_mfma_f32_16x16x32_bf16(a1, b1, acc[1][1], 0, 0, 0);
    }

#pragma unroll
    for (int mi = 0; mi < 2; mi++) {
#pragma unroll
        for (int ni = 0; ni < 2; ni++) {
            int col = n0 + wn * 32 + ni * 16 + r;
            if (col < N) {
                int rowb = m0 + wm * 32 + mi * 16 + (q << 2);
                float bsv = BIAS ? bias[col] : 0.f;
#pragma unroll
                for (int j = 0; j < 4; j++) {
                    float val = acc[mi][ni][j] + bsv;
                    if (GELU_) {
                        float u = val;
                        val = 0.5f * u * (1.f + tanhf(0.7978845608028654f * (u + 0.044715f * u * u * u)));
                    }
                    size_t idx = (size_t)(rowb + j) * ldc + col;
                    if (RESID) Cf[idx] += val;
                    else if (OBF16) Cb[idx] = (bf16)val;
                    else Cf[idx] = val;
                }
            }
        }
    }
}

// ---------------- MFMA attention: block per (b,h), 4 waves ----------------
__global__ __launch_bounds__(256) void k_attn(const float* __restrict__ QKV, bf16* __restrict__ O) {
    __shared__ __align__(16) bf16 Qs[128][40];
    __shared__ __align__(16) bf16 Ks[128][40];
    __shared__ __align__(16) bf16 VT[32][136];
    __shared__ __align__(16) bf16 PT[128][136];
    __shared__ float Ls[128];
    int tid = threadIdx.x;
    int lane = tid & 63, w = tid >> 6;
    int l5 = lane >> 5, l31 = lane & 31;
    int b = blockIdx.x >> 3, h = blockIdx.x & 7;

    {
        int t = tid & 127, half = tid >> 7, d0 = half * 16;
        size_t rowb = (size_t)(b * T_ + t) * 768 + h * HD_ + d0;
        bf16 tq[16], tk[16];
#pragma unroll
        for (int i4 = 0; i4 < 4; i4++) {
            float4 qv = *(const float4*)&QKV[rowb + 4 * i4];
            float4 kv = *(const float4*)&QKV[rowb + 256 + 4 * i4];
            float4 vv = *(const float4*)&QKV[rowb + 512 + 4 * i4];
            tq[4 * i4] = (bf16)qv.x; tq[4 * i4 + 1] = (bf16)qv.y; tq[4 * i4 + 2] = (bf16)qv.z; tq[4 * i4 + 3] = (bf16)qv.w;
            tk[4 * i4] = (bf16)kv.x; tk[4 * i4 + 1] = (bf16)kv.y; tk[4 * i4 + 2] = (bf16)kv.z; tk[4 * i4 + 3] = (bf16)kv.w;
            VT[d0 + 4 * i4][t]     = (bf16)vv.x;
            VT[d0 + 4 * i4 + 1][t] = (bf16)vv.y;
            VT[d0 + 4 * i4 + 2][t] = (bf16)vv.z;
            VT[d0 + 4 * i4 + 3][t] = (bf16)vv.w;
        }
        *(bf16x8*)&Qs[t][d0]     = *(bf16x8*)&tq[0];
        *(bf16x8*)&Qs[t][d0 + 8] = *(bf16x8*)&tq[8];
        *(bf16x8*)&Ks[t][d0]     = *(bf16x8*)&tk[0];
        *(bf16x8*)&Ks[t][d0 + 8] = *(bf16x8*)&tk[8];
    }
    __syncthreads();

    const float scale = 0.17677669529663687f;
#pragma unroll
    for (int qt = 0; qt < 4; qt++) {
        f32x16 acc = {};
        bf16x8 a0 = *(const bf16x8*)&Ks[32 * w + l31][8 * l5];
        bf16x8 b0 = *(const bf16x8*)&Qs[32 * qt + l31][8 * l5];
        acc = __builtin_amdgcn_mfma_f32_32x32x16_bf16(a0, b0, acc, 0, 0, 0);
        bf16x8 a1 = *(const bf16x8*)&Ks[32 * w + l31][16 + 8 * l5];
        bf16x8 b1 = *(const bf16x8*)&Qs[32 * qt + l31][16 + 8 * l5];
        acc = __builtin_amdgcn_mfma_f32_32x32x16_bf16(a1, b1, acc, 0, 0, 0);
        int qg = 32 * qt + l31;
#pragma unroll
        for (int r = 0; r < 16; r++) {
            int key = 32 * w + (r & 3) + 8 * (r >> 2) + 4 * l5;
            float p = (key <= qg) ? expf(acc[r] * scale) : 0.f;
            PT[qg][key] = (bf16)p;
        }
    }
    __syncthreads();

    if (tid < 128) {
        float s = 0.f;
#pragma unroll
        for (int kk = 0; kk < 128; kk += 8) {
            bf16x8 v = *(const bf16x8*)&PT[tid][kk];
#pragma unroll
            for (int j = 0; j < 8; j++) s += (float)v[j];
        }
        Ls[tid] = 1.f / s;
    }

    f32x16 oacc = {};
#pragma unroll
    for (int kap = 0; kap < 8; kap++) {
        bf16x8 af = *(const bf16x8*)&PT[32 * w + l31][16 * kap + 8 * l5];
        bf16x8 bv = *(const bf16x8*)&VT[l31][16 * kap + 8 * l5];
        oacc = __builtin_amdgcn_mfma_f32_32x32x16_bf16(af, bv, oacc, 0, 0, 0);
    }
    __syncthreads();
#pragma unroll
    for (int r = 0; r < 16; r++) {
        int qg = 32 * w + (r & 3) + 8 * (r >> 2) + 4 * l5;
        O[(size_t)(b * T_ + qg) * D_ + h * HD_ + l31] = (bf16)(oacc[r] * Ls[qg]);
    }
}

// ---------------- fused scan (blocks 0-3) + logits (blocks 4-503) ----------------
// Scan: v4 structure (head-per-wave, MFMA GEMV, register state), HIF values prefetched
// from global per step (no hifc LDS). Publishes rv->Abig then releases flag.
// Logits: stage B slice in LDS (overlaps scan), spin on flag, then full-K loop.
union SPool {
    struct { bf16 rvh[T_][128]; __align__(16) bf16 rvb[2][128]; } scan;
    struct { __align__(16) bf16 BsT[64][392]; } log;
};

__global__ __launch_bounds__(256) void k_scan_logits(const float* __restrict__ Wif,
                                                     const float* __restrict__ HIF,
                                                     bf16* __restrict__ Abig,
                                                     const float* __restrict__ Bm,
                                                     const float* __restrict__ bias,
                                                     float* __restrict__ C,
                                                     unsigned* __restrict__ flags) {
    __shared__ SPool sp;
    int tid = threadIdx.x;
    int lane = tid & 63, w = tid >> 6;

    if (blockIdx.x < 4) {
        // ================= SCAN =================
        int b = blockIdx.x;
        int r = lane & 15, q = lane >> 4;
        int d = lane & 31;

        bf16x8 bfrag[5][4];
#pragma unroll
        for (int ti = 0; ti < 5; ti++) {
#pragma unroll
            for (int kap = 0; kap < 4; kap++) {
                bf16x8 v;
#pragma unroll
                for (int j = 0; j < 8; j++) {
                    int k = 32 * kap + 8 * q + j;
                    float wv_ = 0.f;
                    if (ti < 4) {
                        int fl = w * 129 + 64 + 16 * ti + r;
                        wv_ = Wif[(size_t)(256 + k) * NC_ + fl];
                    } else if (r == 0) {
                        wv_ = Wif[(size_t)(256 + k) * NC_ + (w * 129 + 128)];
                    }
                    v[j] = (bf16)wv_;
                }
                bfrag[ti][kap] = v;
            }
        }

        const float* HB = HIF + (size_t)(b * T_) * NC_ + w * 129;
        float hw_n = HB[64 + d], he_n = HB[96 + d], ha_n = HB[128];

        if (tid < 128) sp.scan.rvb[0][tid] = (bf16)0.f;
        float rv1 = 0.f, mm1 = 0.f;
        __syncthreads();

        for (int t = 0; t < T_; t++) {
            const bf16* rb = &sp.scan.rvb[t & 1][0];
            bf16x8 afr0 = *(const bf16x8*)&rb[8 * q];
            bf16x8 afr1 = *(const bf16x8*)&rb[32 + 8 * q];
            bf16x8 afr2 = *(const bf16x8*)&rb[64 + 8 * q];
            bf16x8 afr3 = *(const bf16x8*)&rb[96 + 8 * q];

            float hw = hw_n, he = he_n, ha = ha_n;
            if (t + 1 < T_) {
                const float* Hr = HB + (size_t)(t + 1) * NC_;
                hw_n = Hr[64 + d]; he_n = Hr[96 + d]; ha_n = Hr[128];
            }

            float tv[5];
#pragma unroll
            for (int ti = 0; ti < 5; ti++) {
                f32x4 a0 = {}, a1 = {};
                a0 = __builtin_amdgcn_mfma_f32_16x16x32_bf16(afr0, bfrag[ti][0], a0, 0, 0, 0);
                a1 = __builtin_amdgcn_mfma_f32_16x16x32_bf16(afr1, bfrag[ti][1], a1, 0, 0, 0);
                a0 = __builtin_amdgcn_mfma_f32_16x16x32_bf16(afr2, bfrag[ti][2], a0, 0, 0, 0);
                a1 = __builtin_amdgcn_mfma_f32_16x16x32_bf16(afr3, bfrag[ti][3], a1, 0, 0, 0);
                tv[ti] = a0[0] + a1[0];
            }
            float wv0 = __shfl(tv[0], r), wv1 = __shfl(tv[1], r);
            float er0 = __shfl(tv[2], r), er1 = __shfl(tv[3], r);
            float gv  = __shfl(tv[4], 0);
            float gw = (d < 16) ? wv0 : wv1;
            float ge = (d < 16) ? er0 : er1;

            if (lane < 32) {
                float gwv = gw + hw;
                float gev = ge + he;
                float gav = gv + ha;
                float er = 1.f / (1.f + expf(-gev));
                float ag = 1.f / (1.f + expf(-gav));
                sp.scan.rvh[t][32 * w + d] = (bf16)rv1;
                float mn = mm1 * (1.f - er * (1.f / 512.f)) + ag * (1.f / 512.f) * gwv;
                rv1 += mm1;
                mm1 = mn;
                sp.scan.rvb[(t + 1) & 1][32 * w + d] = (bf16)rv1;
            }
            __syncthreads();
        }

        for (int idx = tid; idx < T_ * 128; idx += 256) {
            int t = idx >> 7, dd = idx & 127;
            Abig[(size_t)(b * T_ + t) * KBIG_ + 256 + dd] = sp.scan.rvh[t][dd];
        }
        __threadfence();
        __syncthreads();
        if (tid == 0) atomicAdd(&flags[0], 1u);
        return;
    }

    // ================= LOGITS =================
    int wm = w >> 1, wn = w & 1;
    int n0 = (blockIdx.x - 4) * 64;

    int bn = tid & 63, bk = (tid >> 6) << 3;
#pragma unroll
    for (int k0 = 0; k0 < KBIG_; k0 += 32) {
        bf16x8 bv;
#pragma unroll
        for (int e = 0; e < 8; e++) bv[e] = (bf16)Bm[(size_t)(k0 + bk + e) * VOCAB_ + n0 + bn];
        *(bf16x8*)&sp.log.BsT[bn][k0 + bk] = bv;
    }

    float bsv[2];
#pragma unroll
    for (int ni = 0; ni < 2; ni++) bsv[ni] = bias[n0 + wn * 32 + ni * 16 + (lane & 15)];

    // wait for scan completion (rv columns of Abig)
    if (tid == 0) {
        while (atomicAdd(&flags[0], 0u) < 4u) __builtin_amdgcn_s_sleep(32);
    }
    __syncthreads();
    __threadfence();

    const bf16* A = Abig;
    int kfrag = (lane >> 4) << 3;
    for (int mt = 0; mt < 8; mt++) {
        int m0 = mt * 64;
        f32x4 acc[2][2] = {};
#pragma unroll
        for (int kk = 0; kk < KBIG_; kk += 32) {
            bf16x8 af[2], bfv[2];
#pragma unroll
            for (int mi = 0; mi < 2; mi++)
                af[mi] = *(const bf16x8*)&A[(size_t)(m0 + wm * 32 + mi * 16 + (lane & 15)) * KBIG_ + kk + kfrag];
#pragma unroll
            for (int ni = 0; ni < 2; ni++)
                bfv[ni] = *(const bf16x8*)&sp.log.BsT[wn * 32 + ni * 16 + (lane & 15)][kk + kfrag];
#pragma unroll
            for (int mi = 0; mi < 2; mi++)
#pragma unroll
                for (int ni = 0; ni < 2; ni++)
                    acc[mi][ni] = __builtin_amdgcn_mfma_f32_16x16x32_bf16(af[mi], bfv[ni], acc[mi][ni], 0, 0, 0);
        }
#pragma unroll
        for (int mi = 0; mi < 2; mi++) {
#pragma unroll
            for (int ni = 0; ni < 2; ni++) {
                int colg = n0 + wn * 32 + ni * 16 + (lane & 15);
                int rowb = m0 + wm * 32 + mi * 16 + ((lane >> 4) << 2);
#pragma unroll
                for (int j = 0; j < 4; j++)
                    C[(size_t)(rowb + j) * VOCAB_ + colg] = acc[mi][ni][j] + bsv[ni];
            }
        }
    }
}

extern "C" void kernel_launch(void* const* d_in, const int* in_sizes, int n_in,
                              void* d_out, int out_size, void* d_ws, size_t ws_size,
                              hipStream_t stream) {
    const int*   ids  = (const int*)d_in[0];
    const float* tok  = (const float*)d_in[1];
    const float* pos  = (const float*)d_in[2];
    const float* Wqkv = (const float*)d_in[3];
    const float* Wo   = (const float*)d_in[4];
    const float* ln1g = (const float*)d_in[5];
    const float* ln1b = (const float*)d_in[6];
    const float* ln2g = (const float*)d_in[7];
    const float* ln2b = (const float*)d_in[8];
    const float* W1   = (const float*)d_in[9];
    const float* b1   = (const float*)d_in[10];
    const float* W2   = (const float*)d_in[11];
    const float* b2   = (const float*)d_in[12];
    const float* lnfg = (const float*)d_in[13];
    const float* lnfb = (const float*)d_in[14];
    const float* Wl   = (const float*)d_in[15];
    const float* bl   = (const float*)d_in[16];
    const float* Wif  = (const float*)d_in[17];
    const float* bif  = (const float*)d_in[18];

    char* ws = (char*)d_ws;
    float* X    = (float*)(ws + 0);
    float* QKV  = (float*)(ws + 524288);
    bf16*  Hb   = (bf16*)(ws + 2097152);
    bf16*  Obf  = (bf16*)(ws + 2359296);
    bf16*  FF1  = (bf16*)(ws + 2621440);
    float* HIF  = (float*)(ws + 3670016);
    bf16*  Abig = (bf16*)(ws + 4726784);
    bf16*  WqkvT= (bf16*)(ws + 5120000);
    bf16*  WoT  = (bf16*)(ws + 5906432);
    bf16*  W1T  = (bf16*)(ws + 6168576);
    bf16*  W2T  = (bf16*)(ws + 7217152);
    bf16*  WifT = (bf16*)(ws + 8265728);
    unsigned* flags = (unsigned*)(ws + 8560640);
    float* outp = (float*)d_out;

    TJobs js;
    int blk = 0;
    auto setj = [&](int i, const float* s, bf16* d, int K, int N, int Npad) {
        js.j[i] = {s, d, K, N, blk};
        blk += (K >> 6) * (Npad >> 6);
    };
    setj(0, Wqkv,              WqkvT,              256, 768, 768);
    setj(1, Wqkv + 256 * 768,  WqkvT + 768 * 256,  256, 768, 768);
    setj(2, Wo,                WoT,                256, 256, 256);
    setj(3, Wo + 256 * 256,    WoT + 256 * 256,    256, 256, 256);
    setj(4, W1,                W1T,                256, 1024, 1024);
    setj(5, W1 + 256 * 1024,   W1T + 1024 * 256,   256, 1024, 1024);
    setj(6, W2,                W2T,                1024, 256, 256);
    setj(7, W2 + 1024 * 256,   W2T + 256 * 1024,   1024, 256, 256);
    setj(8, Wif,               WifT,               256, NC_, 576);

    k_tr_embed<<<blk + 512, 256, 0, stream>>>(js, ids, tok, pos, ln1g, ln1b, X, Hb, flags);

    for (int l = 0; l < 2; l++) {
        k_dgemm<false, false, false, false><<<dim3(12, 8), 256, 0, stream>>>(
            Hb, D_, WqkvT + (size_t)l * 768 * 256, nullptr, QKV, nullptr, 768, 768, 256);
        k_attn<<<32, 256, 0, stream>>>(QKV, Obf);
        k_dgemm<false, false, true, false><<<dim3(4, 8), 256, 0, stream>>>(
            Obf, D_, WoT + (size_t)l * 256 * 256, nullptr, X, nullptr, D_, D_, 256);
        k_ln<<<512, 256, 0, stream>>>(X, ln2g + l * D_, ln2b + l * D_, Hb, D_);
        k_dgemm<true, true, false, true><<<dim3(16, 8), 256, 0, stream>>>(
            Hb, D_, W1T + (size_t)l * 1024 * 256, b1 + l * FF_, nullptr, FF1, FF_, FF_, 256);
        k_dgemm<true, false, true, false><<<dim3(4, 8), 256, 0, stream>>>(
            FF1, FF_, W2T + (size_t)l * 256 * 1024, b2 + l * D_, X, nullptr, D_, D_, 1024);
        if (l == 0)
            k_ln<<<512, 256, 0, stream>>>(X, ln1g + D_, ln1b + D_, Hb, D_);
    }

    k_ln<<<512, 256, 0, stream>>>(X, lnfg, lnfb, Abig, KBIG_);
    k_dgemm<true, false, false, false><<<dim3(9, 8), 256, 0, stream>>>(
        Abig, KBIG_, WifT, bif, HIF, nullptr, NC_, NC_, 256);
    k_scan_logits<<<504, 256, 0, stream>>>(Wif, HIF, Abig, Wl, bl, outp, flags);
}

// Round 13
// 277.505 us; speedup vs baseline: 1.0201x; 1.0201x over previous
//
#include <hip/hip_runtime.h>
#include <hip/hip_bf16.h>
#include <math.h>

typedef __bf16 bf16;
typedef __bf16 bf16x8 __attribute__((ext_vector_type(8)));
typedef float f32x4 __attribute__((ext_vector_type(4)));
typedef float f32x16 __attribute__((ext_vector_type(16)));

#define B_ 4
#define T_ 128
#define D_ 256
#define FF_ 1024
#define HD_ 32
#define VOCAB_ 32000
#define NC_ 516    // iface cols = MH*(4*HD+1)
#define KBIG_ 384  // D + MD

// ---------------- weight transpose (blocks 0..419) + embed+LN1 (blocks 420..931) ----------------
struct TJob { const float* src; bf16* dst; int K; int N; int blk0; };
struct TJobs { TJob j[9]; };
__global__ __launch_bounds__(256) void k_tr_embed(TJobs js, const int* __restrict__ ids,
                                                  const float* __restrict__ tok,
                                                  const float* __restrict__ pos,
                                                  const float* __restrict__ g,
                                                  const float* __restrict__ b,
                                                  float* __restrict__ X, bf16* __restrict__ out,
                                                  unsigned* __restrict__ flags) {
    int bid = blockIdx.x;
    if (bid == 0 && threadIdx.x == 0) flags[0] = 0u;   // reset handshake for this launch
    if (bid < 420) {
        __shared__ float tile[64][65];
        int r = 0;
#pragma unroll
        for (int i = 1; i < 9; i++) if (bid >= js.j[i].blk0) r = i;
        TJob jb = js.j[r];
        int local = bid - jb.blk0;
        int tiles_k = jb.K >> 6;
        int ik = local % tiles_k, in = local / tiles_k;
        int k0 = ik * 64, n0 = in * 64;
        int tx = threadIdx.x & 63, ty = threadIdx.x >> 6;
#pragma unroll
        for (int rr = 0; rr < 64; rr += 4) {
            int kk = k0 + rr + ty, nn = n0 + tx;
            tile[rr + ty][tx] = (nn < jb.N) ? jb.src[(size_t)kk * jb.N + nn] : 0.f;
        }
        __syncthreads();
#pragma unroll
        for (int rr = 0; rr < 64; rr += 4) {
            int nn = n0 + rr + ty, kk = k0 + tx;
            jb.dst[(size_t)nn * jb.K + kk] = (bf16)tile[tx][rr + ty];
        }
        return;
    }
    // embed + LN1(layer0)
    int row = bid - 420;
    int d   = threadIdx.x;
    int t   = row & (T_ - 1);
    int id  = ids[row];
    float v = tok[(size_t)id * D_ + d] + pos[(size_t)t * D_ + d];
    X[(size_t)row * D_ + d] = v;
    float s1 = v, s2 = v * v;
#pragma unroll
    for (int off = 32; off > 0; off >>= 1) {
        s1 += __shfl_xor(s1, off);
        s2 += __shfl_xor(s2, off);
    }
    __shared__ float r1[4], r2[4];
    int wid = d >> 6, lane = d & 63;
    if (lane == 0) { r1[wid] = s1; r2[wid] = s2; }
    __syncthreads();
    float tot1 = r1[0] + r1[1] + r1[2] + r1[3];
    float tot2 = r2[0] + r2[1] + r2[2] + r2[3];
    float mean = tot1 * (1.f / D_);
    float var  = tot2 * (1.f / D_) - mean * mean;
    float rs   = rsqrtf(var + 1e-5f);
    out[(size_t)row * D_ + d] = (bf16)((v - mean) * rs * g[d] + b[d]);
}

// ---------------- layernorm (row of 256) -> bf16 out ----------------
__global__ void k_ln(const float* __restrict__ X, const float* __restrict__ g,
                     const float* __restrict__ b, bf16* __restrict__ out, int ostride) {
    int row = blockIdx.x;
    int d   = threadIdx.x;
    float v = X[(size_t)row * D_ + d];
    float s1 = v, s2 = v * v;
#pragma unroll
    for (int off = 32; off > 0; off >>= 1) {
        s1 += __shfl_xor(s1, off);
        s2 += __shfl_xor(s2, off);
    }
    __shared__ float r1[4], r2[4];
    int wid = d >> 6, lane = d & 63;
    if (lane == 0) { r1[wid] = s1; r2[wid] = s2; }
    __syncthreads();
    float tot1 = r1[0] + r1[1] + r1[2] + r1[3];
    float tot2 = r2[0] + r2[1] + r2[2] + r2[3];
    float mean = tot1 * (1.f / D_);
    float var  = tot2 * (1.f / D_) - mean * mean;
    float rs   = rsqrtf(var + 1e-5f);
    out[(size_t)row * ostride + d] = (bf16)((v - mean) * rs * g[d] + b[d]);
}

// ---------------- direct-fragment GEMM (no LDS, no barriers) ----------------
template <bool BIAS, bool GELU_, bool RESID, bool OBF16>
__global__ __launch_bounds__(256) void k_dgemm(const bf16* __restrict__ A, int lda,
                                               const bf16* __restrict__ BT,
                                               const float* __restrict__ bias,
                                               float* __restrict__ Cf, bf16* __restrict__ Cb,
                                               int ldc, int N, int K) {
    int tid = threadIdx.x;
    int lane = tid & 63, wid = tid >> 6;
    int wm = wid >> 1, wn = wid & 1;
    int m0 = blockIdx.y * 64, n0 = blockIdx.x * 64;
    int r = lane & 15, q = lane >> 4;

    const bf16* Ab = A  + (size_t)(m0 + wm * 32 + r) * lda + q * 8;
    const bf16* Bb = BT + (size_t)(n0 + wn * 32 + r) * K   + q * 8;

    f32x4 acc[2][2] = {};
#pragma unroll 4
    for (int k0 = 0; k0 < K; k0 += 32) {
        bf16x8 a0 = *(const bf16x8*)(Ab + k0);
        bf16x8 a1 = *(const bf16x8*)(Ab + (size_t)16 * lda + k0);
        bf16x8 b0 = *(const bf16x8*)(Bb + k0);
        bf16x8 b1 = *(const bf16x8*)(Bb + (size_t)16 * K + k0);
        acc[0][0] = __builtin_amdgcn_mfma_f32_16x16x32_bf16(a0, b0, acc[0][0], 0, 0, 0);
        acc[0][1] = __builtin_amdgcn_mfma_f32_16x16x32_bf16(a0, b1, acc[0][1], 0, 0, 0);
        acc[1][0] = __builtin_amdgcn_mfma_f32_16x16x32_bf16(a1, b0, acc[1][0], 0, 0, 0);
        acc[1][1] = __builtin_amdgcn_mfma_f32_16x16x32_bf16(a1, b1, acc[1][1], 0, 0, 0);
    }

#pragma unroll
    for (int mi = 0; mi < 2; mi++) {
#pragma unroll
        for (int ni = 0; ni < 2; ni++) {
            int col = n0 + wn * 32 + ni * 16 + r;
            if (col < N) {
                int rowb = m0 + wm * 32 + mi * 16 + (q << 2);
                float bsv = BIAS ? bias[col] : 0.f;
#pragma unroll
                for (int j = 0; j < 4; j++) {
                    float val = acc[mi][ni][j] + bsv;
                    if (GELU_) {
                        float u = val;
                        val = 0.5f * u * (1.f + tanhf(0.7978845608028654f * (u + 0.044715f * u * u * u)));
                    }
                    size_t idx = (size_t)(rowb + j) * ldc + col;
                    if (RESID) Cf[idx] += val;
                    else if (OBF16) Cb[idx] = (bf16)val;
                    else Cf[idx] = val;
                }
            }
        }
    }
}

// ---------------- MFMA attention: block per (b,h), 4 waves ----------------
__global__ __launch_bounds__(256) void k_attn(const float* __restrict__ QKV, bf16* __restrict__ O) {
    __shared__ __align__(16) bf16 Qs[128][40];
    __shared__ __align__(16) bf16 Ks[128][40];
    __shared__ __align__(16) bf16 VT[32][136];
    __shared__ __align__(16) bf16 PT[128][136];
    __shared__ float Ls[128];
    int tid = threadIdx.x;
    int lane = tid & 63, w = tid >> 6;
    int l5 = lane >> 5, l31 = lane & 31;
    int b = blockIdx.x >> 3, h = blockIdx.x & 7;

    {
        int t = tid & 127, half = tid >> 7, d0 = half * 16;
        size_t rowb = (size_t)(b * T_ + t) * 768 + h * HD_ + d0;
        bf16 tq[16], tk[16];
#pragma unroll
        for (int i4 = 0; i4 < 4; i4++) {
            float4 qv = *(const float4*)&QKV[rowb + 4 * i4];
            float4 kv = *(const float4*)&QKV[rowb + 256 + 4 * i4];
            float4 vv = *(const float4*)&QKV[rowb + 512 + 4 * i4];
            tq[4 * i4] = (bf16)qv.x; tq[4 * i4 + 1] = (bf16)qv.y; tq[4 * i4 + 2] = (bf16)qv.z; tq[4 * i4 + 3] = (bf16)qv.w;
            tk[4 * i4] = (bf16)kv.x; tk[4 * i4 + 1] = (bf16)kv.y; tk[4 * i4 + 2] = (bf16)kv.z; tk[4 * i4 + 3] = (bf16)kv.w;
            VT[d0 + 4 * i4][t]     = (bf16)vv.x;
            VT[d0 + 4 * i4 + 1][t] = (bf16)vv.y;
            VT[d0 + 4 * i4 + 2][t] = (bf16)vv.z;
            VT[d0 + 4 * i4 + 3][t] = (bf16)vv.w;
        }
        *(bf16x8*)&Qs[t][d0]     = *(bf16x8*)&tq[0];
        *(bf16x8*)&Qs[t][d0 + 8] = *(bf16x8*)&tq[8];
        *(bf16x8*)&Ks[t][d0]     = *(bf16x8*)&tk[0];
        *(bf16x8*)&Ks[t][d0 + 8] = *(bf16x8*)&tk[8];
    }
    __syncthreads();

    const float scale = 0.17677669529663687f;
#pragma unroll
    for (int qt = 0; qt < 4; qt++) {
        f32x16 acc = {};
        bf16x8 a0 = *(const bf16x8*)&Ks[32 * w + l31][8 * l5];
        bf16x8 b0 = *(const bf16x8*)&Qs[32 * qt + l31][8 * l5];
        acc = __builtin_amdgcn_mfma_f32_32x32x16_bf16(a0, b0, acc, 0, 0, 0);
        bf16x8 a1 = *(const bf16x8*)&Ks[32 * w + l31][16 + 8 * l5];
        bf16x8 b1 = *(const bf16x8*)&Qs[32 * qt + l31][16 + 8 * l5];
        acc = __builtin_amdgcn_mfma_f32_32x32x16_bf16(a1, b1, acc, 0, 0, 0);
        int qg = 32 * qt + l31;
#pragma unroll
        for (int r = 0; r < 16; r++) {
            int key = 32 * w + (r & 3) + 8 * (r >> 2) + 4 * l5;
            float p = (key <= qg) ? expf(acc[r] * scale) : 0.f;
            PT[qg][key] = (bf16)p;
        }
    }
    __syncthreads();

    if (tid < 128) {
        float s = 0.f;
#pragma unroll
        for (int kk = 0; kk < 128; kk += 8) {
            bf16x8 v = *(const bf16x8*)&PT[tid][kk];
#pragma unroll
            for (int j = 0; j < 8; j++) s += (float)v[j];
        }
        Ls[tid] = 1.f / s;
    }

    f32x16 oacc = {};
#pragma unroll
    for (int kap = 0; kap < 8; kap++) {
        bf16x8 af = *(const bf16x8*)&PT[32 * w + l31][16 * kap + 8 * l5];
        bf16x8 bv = *(const bf16x8*)&VT[l31][16 * kap + 8 * l5];
        oacc = __builtin_amdgcn_mfma_f32_32x32x16_bf16(af, bv, oacc, 0, 0, 0);
    }
    __syncthreads();
#pragma unroll
    for (int r = 0; r < 16; r++) {
        int qg = 32 * w + (r & 3) + 8 * (r >> 2) + 4 * l5;
        O[(size_t)(b * T_ + qg) * D_ + h * HD_ + l31] = (bf16)(oacc[r] * Ls[qg]);
    }
}

// ---------------- fused scan (blocks 0-3) + split-K logits (blocks 4-503) ----------------
// Scan: v4 structure; HIF prefetched 1 step ahead (global loads stay in flight across the
// RAW s_barrier — no vmcnt drain); rv streamed to Abig as fire-and-forget stores.
// Logits: stage B, compute K=0..255 (lnf part, ready at launch) DURING the scan, wait
// flag, finish K=256..383 (rv part).
union SPool {
    struct { __align__(16) bf16 rvb[2][128]; } scan;
    struct { __align__(16) bf16 BsT[64][392]; } log;
};

__global__ __launch_bounds__(256) void k_scan_logits(const float* __restrict__ Wif,
                                                     const float* __restrict__ HIF,
                                                     bf16* __restrict__ Abig,
                                                     const float* __restrict__ Bm,
                                                     const float* __restrict__ bias,
                                                     float* __restrict__ C,
                                                     unsigned* __restrict__ flags) {
    __shared__ SPool sp;
    int tid = threadIdx.x;
    int lane = tid & 63, w = tid >> 6;

    if (blockIdx.x < 4) {
        // ================= SCAN =================
        int b = blockIdx.x;
        int r = lane & 15, q = lane >> 4;
        int d = lane & 31;

        bf16x8 bfrag[5][4];
#pragma unroll
        for (int ti = 0; ti < 5; ti++) {
#pragma unroll
            for (int kap = 0; kap < 4; kap++) {
                bf16x8 v;
#pragma unroll
                for (int j = 0; j < 8; j++) {
                    int k = 32 * kap + 8 * q + j;
                    float wv_ = 0.f;
                    if (ti < 4) {
                        int fl = w * 129 + 64 + 16 * ti + r;
                        wv_ = Wif[(size_t)(256 + k) * NC_ + fl];
                    } else if (r == 0) {
                        wv_ = Wif[(size_t)(256 + k) * NC_ + (w * 129 + 128)];
                    }
                    v[j] = (bf16)wv_;
                }
                bfrag[ti][kap] = v;
            }
        }

        const float* HB = HIF + (size_t)(b * T_) * NC_ + w * 129;
        float hw_n = HB[64 + d], he_n = HB[96 + d], ha_n = HB[128];
        bf16* Aout = Abig + 256 + 32 * w + d;   // + (b*T+t)*KBIG per step

        if (tid < 128) sp.scan.rvb[0][tid] = (bf16)0.f;
        float rv1 = 0.f, mm1 = 0.f;
        __syncthreads();

        for (int t = 0; t < T_; t++) {
            float hw = hw_n, he = he_n, ha = ha_n;
            if (t + 1 < T_) {   // issue next step's loads; they stay in flight across the barrier
                const float* Hr = HB + (size_t)(t + 1) * NC_;
                hw_n = Hr[64 + d]; he_n = Hr[96 + d]; ha_n = Hr[128];
            }

            const bf16* rb = &sp.scan.rvb[t & 1][0];
            bf16x8 afr0 = *(const bf16x8*)&rb[8 * q];
            bf16x8 afr1 = *(const bf16x8*)&rb[32 + 8 * q];
            bf16x8 afr2 = *(const bf16x8*)&rb[64 + 8 * q];
            bf16x8 afr3 = *(const bf16x8*)&rb[96 + 8 * q];

            float tv[5];
#pragma unroll
            for (int ti = 0; ti < 5; ti++) {
                f32x4 a0 = {}, a1 = {};
                a0 = __builtin_amdgcn_mfma_f32_16x16x32_bf16(afr0, bfrag[ti][0], a0, 0, 0, 0);
                a1 = __builtin_amdgcn_mfma_f32_16x16x32_bf16(afr1, bfrag[ti][1], a1, 0, 0, 0);
                a0 = __builtin_amdgcn_mfma_f32_16x16x32_bf16(afr2, bfrag[ti][2], a0, 0, 0, 0);
                a1 = __builtin_amdgcn_mfma_f32_16x16x32_bf16(afr3, bfrag[ti][3], a1, 0, 0, 0);
                tv[ti] = a0[0] + a1[0];
            }
            float wv0 = __shfl(tv[0], r), wv1 = __shfl(tv[1], r);
            float er0 = __shfl(tv[2], r), er1 = __shfl(tv[3], r);
            float gv  = __shfl(tv[4], 0);
            float gw = (d < 16) ? wv0 : wv1;
            float ge = (d < 16) ? er0 : er1;

            if (lane < 32) {
                float gwv = gw + hw;
                float gev = ge + he;
                float gav = gv + ha;
                float er = 1.f / (1.f + expf(-gev));
                float ag = 1.f / (1.f + expf(-gav));
                Aout[(size_t)(b * T_ + t) * KBIG_] = (bf16)rv1;   // rv at step entry (async store)
                float mn = mm1 * (1.f - er * (1.f / 512.f)) + ag * (1.f / 512.f) * gwv;
                rv1 += mm1;
                mm1 = mn;
                sp.scan.rvb[(t + 1) & 1][32 * w + d] = (bf16)rv1;
            }
            // raw barrier: LDS ordered, global loads/stores remain in flight
            asm volatile("s_waitcnt lgkmcnt(0)" ::: "memory");
            __builtin_amdgcn_s_barrier();
            __builtin_amdgcn_sched_barrier(0);
        }

        asm volatile("s_waitcnt vmcnt(0)" ::: "memory");
        __threadfence();
        __syncthreads();
        if (tid == 0) atomicAdd(&flags[0], 1u);
        return;
    }

    // ================= LOGITS (split-K) =================
    int wm = w >> 1, wn = w & 1;
    int n0 = (blockIdx.x - 4) * 64;
    int rr = lane & 15, q = lane >> 4;
    int kfrag = q << 3;

    int bn = tid & 63, bk = (tid >> 6) << 3;
#pragma unroll
    for (int k0 = 0; k0 < KBIG_; k0 += 32) {
        bf16x8 bv;
#pragma unroll
        for (int e = 0; e < 8; e++) bv[e] = (bf16)Bm[(size_t)(k0 + bk + e) * VOCAB_ + n0 + bn];
        *(bf16x8*)&sp.log.BsT[bn][k0 + bk] = bv;
    }
    __syncthreads();

    float bsv[2];
#pragma unroll
    for (int ni = 0; ni < 2; ni++) bsv[ni] = bias[n0 + wn * 32 + ni * 16 + rr];

    const bf16* A = Abig;
    f32x4 acc[8][2][2] = {};

    // ---- part 1: K = 0..255 (lnf columns of Abig — valid before the scan) ----
#pragma unroll
    for (int kk = 0; kk < 256; kk += 32) {
        bf16x8 bfv[2];
#pragma unroll
        for (int ni = 0; ni < 2; ni++)
            bfv[ni] = *(const bf16x8*)&sp.log.BsT[wn * 32 + ni * 16 + rr][kk + kfrag];
#pragma unroll
        for (int mt = 0; mt < 8; mt++) {
            bf16x8 af[2];
#pragma unroll
            for (int mi = 0; mi < 2; mi++)
                af[mi] = *(const bf16x8*)&A[(size_t)(mt * 64 + wm * 32 + mi * 16 + rr) * KBIG_ + kk + kfrag];
#pragma unroll
            for (int mi = 0; mi < 2; mi++)
#pragma unroll
                for (int ni = 0; ni < 2; ni++)
                    acc[mt][mi][ni] = __builtin_amdgcn_mfma_f32_16x16x32_bf16(af[mi], bfv[ni], acc[mt][mi][ni], 0, 0, 0);
        }
    }

    // ---- wait for scan ----
    if (tid == 0) {
        while (atomicAdd(&flags[0], 0u) < 4u) __builtin_amdgcn_s_sleep(32);
    }
    __syncthreads();
    __threadfence();

    // ---- part 2: K = 256..383 (rv columns) ----
#pragma unroll
    for (int kk = 256; kk < KBIG_; kk += 32) {
        bf16x8 bfv[2];
#pragma unroll
        for (int ni = 0; ni < 2; ni++)
            bfv[ni] = *(const bf16x8*)&sp.log.BsT[wn * 32 + ni * 16 + rr][kk + kfrag];
#pragma unroll
        for (int mt = 0; mt < 8; mt++) {
            bf16x8 af[2];
#pragma unroll
            for (int mi = 0; mi < 2; mi++)
                af[mi] = *(const bf16x8*)&A[(size_t)(mt * 64 + wm * 32 + mi * 16 + rr) * KBIG_ + kk + kfrag];
#pragma unroll
            for (int mi = 0; mi < 2; mi++)
#pragma unroll
                for (int ni = 0; ni < 2; ni++)
                    acc[mt][mi][ni] = __builtin_amdgcn_mfma_f32_16x16x32_bf16(af[mi], bfv[ni], acc[mt][mi][ni], 0, 0, 0);
        }
    }

#pragma unroll
    for (int mt = 0; mt < 8; mt++) {
#pragma unroll
        for (int mi = 0; mi < 2; mi++) {
#pragma unroll
            for (int ni = 0; ni < 2; ni++) {
                int colg = n0 + wn * 32 + ni * 16 + rr;
                int rowb = mt * 64 + wm * 32 + mi * 16 + (q << 2);
#pragma unroll
                for (int j = 0; j < 4; j++)
                    C[(size_t)(rowb + j) * VOCAB_ + colg] = acc[mt][mi][ni][j] + bsv[ni];
            }
        }
    }
}

extern "C" void kernel_launch(void* const* d_in, const int* in_sizes, int n_in,
                              void* d_out, int out_size, void* d_ws, size_t ws_size,
                              hipStream_t stream) {
    const int*   ids  = (const int*)d_in[0];
    const float* tok  = (const float*)d_in[1];
    const float* pos  = (const float*)d_in[2];
    const float* Wqkv = (const float*)d_in[3];
    const float* Wo   = (const float*)d_in[4];
    const float* ln1g = (const float*)d_in[5];
    const float* ln1b = (const float*)d_in[6];
    const float* ln2g = (const float*)d_in[7];
    const float* ln2b = (const float*)d_in[8];
    const float* W1   = (const float*)d_in[9];
    const float* b1   = (const float*)d_in[10];
    const float* W2   = (const float*)d_in[11];
    const float* b2   = (const float*)d_in[12];
    const float* lnfg = (const float*)d_in[13];
    const float* lnfb = (const float*)d_in[14];
    const float* Wl   = (const float*)d_in[15];
    const float* bl   = (const float*)d_in[16];
    const float* Wif  = (const float*)d_in[17];
    const float* bif  = (const float*)d_in[18];

    char* ws = (char*)d_ws;
    float* X    = (float*)(ws + 0);
    float* QKV  = (float*)(ws + 524288);
    bf16*  Hb   = (bf16*)(ws + 2097152);
    bf16*  Obf  = (bf16*)(ws + 2359296);
    bf16*  FF1  = (bf16*)(ws + 2621440);
    float* HIF  = (float*)(ws + 3670016);
    bf16*  Abig = (bf16*)(ws + 4726784);
    bf16*  WqkvT= (bf16*)(ws + 5120000);
    bf16*  WoT  = (bf16*)(ws + 5906432);
    bf16*  W1T  = (bf16*)(ws + 6168576);
    bf16*  W2T  = (bf16*)(ws + 7217152);
    bf16*  WifT = (bf16*)(ws + 8265728);
    unsigned* flags = (unsigned*)(ws + 8560640);
    float* outp = (float*)d_out;

    TJobs js;
    int blk = 0;
    auto setj = [&](int i, const float* s, bf16* d, int K, int N, int Npad) {
        js.j[i] = {s, d, K, N, blk};
        blk += (K >> 6) * (Npad >> 6);
    };
    setj(0, Wqkv,              WqkvT,              256, 768, 768);
    setj(1, Wqkv + 256 * 768,  WqkvT + 768 * 256,  256, 768, 768);
    setj(2, Wo,                WoT,                256, 256, 256);
    setj(3, Wo + 256 * 256,    WoT + 256 * 256,    256, 256, 256);
    setj(4, W1,                W1T,                256, 1024, 1024);
    setj(5, W1 + 256 * 1024,   W1T + 1024 * 256,   256, 1024, 1024);
    setj(6, W2,                W2T,                1024, 256, 256);
    setj(7, W2 + 1024 * 256,   W2T + 256 * 1024,   1024, 256, 256);
    setj(8, Wif,               WifT,               256, NC_, 576);

    k_tr_embed<<<blk + 512, 256, 0, stream>>>(js, ids, tok, pos, ln1g, ln1b, X, Hb, flags);

    for (int l = 0; l < 2; l++) {
        k_dgemm<false, false, false, false><<<dim3(12, 8), 256, 0, stream>>>(
            Hb, D_, WqkvT + (size_t)l * 768 * 256, nullptr, QKV, nullptr, 768, 768, 256);
        k_attn<<<32, 256, 0, stream>>>(QKV, Obf);
        k_dgemm<false, false, true, false><<<dim3(4, 8), 256, 0, stream>>>(
            Obf, D_, WoT + (size_t)l * 256 * 256, nullptr, X, nullptr, D_, D_, 256);
        k_ln<<<512, 256, 0, stream>>>(X, ln2g + l * D_, ln2b + l * D_, Hb, D_);
        k_dgemm<true, true, false, true><<<dim3(16, 8), 256, 0, stream>>>(
            Hb, D_, W1T + (size_t)l * 1024 * 256, b1 + l * FF_, nullptr, FF1, FF_, FF_, 256);
        k_dgemm<true, false, true, false><<<dim3(4, 8), 256, 0, stream>>>(
            FF1, FF_, W2T + (size_t)l * 256 * 1024, b2 + l * D_, X, nullptr, D_, D_, 1024);
        if (l == 0)
            k_ln<<<512, 256, 0, stream>>>(X, ln1g + D_, ln1b + D_, Hb, D_);
    }

    k_ln<<<512, 256, 0, stream>>>(X, lnfg, lnfb, Abig, KBIG_);
    k_dgemm<true, false, false, false><<<dim3(9, 8), 256, 0, stream>>>(
        Abig, KBIG_, WifT, bif, HIF, nullptr, NC_, NC_, 256);
    k_scan_logits<<<504, 256, 0, stream>>>(Wif, HIF, Abig, Wl, bl, outp, flags);
}